// Round 6
// baseline (353.601 us; speedup 1.0000x reference)
//
#include <hip/hip_runtime.h>

#define IMG_H 512
#define IMG_W 512
#define TILE_W 64
#define TILE_H 16
#define LDSW 72   // 64 + 8 halo/alignment cols (covers x0-4 .. x0+67)
#define LDSH 22   // 16 + 6 halo rows (covers y0-3 .. y0+18)
#define NTHREADS 256

// ---------------- compile-time coefficient generation --------------------
// (identical to the verified round-0 kernel)

constexpr double PI_D = 3.141592653589793238462643383279502884;

constexpr double cexp(double x) {
  double term = 1.0, sum = 1.0;
  for (int n = 1; n < 48; ++n) { term *= x / n; sum += term; }
  return sum;
}
constexpr double ccos(double x) {
  double term = 1.0, sum = 1.0;
  for (int n = 1; n < 24; ++n) {
    term *= -x * x / ((2.0 * n - 1.0) * (2.0 * n));
    sum += term;
  }
  return sum;
}
constexpr double csin(double x) {
  double term = x, sum = x;
  for (int n = 1; n < 24; ++n) {
    term *= -x * x / ((2.0 * n) * (2.0 * n + 1.0));
    sum += term;
  }
  return sum;
}
constexpr double cabs_(double x) { return x < 0 ? -x : x; }

struct KTabs {
  float lpf[9];
  float log3[9];
  float log5[25];
  float log7[49];
  float hpf3[9];
  float hpf5[25];
  float gab[4][49];
};

constexpr void fill_log(int ks, double sigma, float* out) {
  double buf[49] = {};
  double s = 0.0;
  const int h = ks / 2;
  for (int i = 0; i < ks; ++i) {
    for (int j = 0; j < ks; ++j) {
      const double xi = (double)(i - h);
      const double yj = (double)(j - h);
      const double r2 = xi * xi + yj * yj;
      const double g = cexp(-r2 / (2.0 * sigma * sigma));
      const double lap = -1.0 / (PI_D * sigma * sigma * sigma * sigma) *
                         (1.0 - r2 / (2.0 * sigma * sigma));
      buf[i * ks + j] = lap * g;
      s += cabs_(lap * g);
    }
  }
  for (int k = 0; k < ks * ks; ++k) out[k] = (float)(buf[k] / s);
}

constexpr void fill_gabor(double ang_deg, float* out) {
  const double th = ang_deg * PI_D / 180.0;
  const double ct = ccos(th), st = csin(th);
  double buf[49] = {};
  double s = 0.0;
  for (int i = 0; i < 7; ++i) {
    for (int j = 0; j < 7; ++j) {
      const double xv = (double)(j - 3);
      const double yv = (double)(i - 3);
      const double xt = xv * ct + yv * st;
      const double yt = -xv * st + yv * ct;
      const double g = cexp(-(xt * xt / 4.0 + yt * yt / 4.0) / 2.0) *
                       ccos(2.0 * PI_D * 0.1 * xt);
      buf[i * 7 + j] = g;
      s += cabs_(g);
    }
  }
  for (int k = 0; k < 49; ++k) out[k] = (float)(buf[k] / s);
}

constexpr KTabs make_tabs() {
  KTabs t{};
  const double lv[9] = {1, 2, 1, 2, 4, 2, 1, 2, 1};
  for (int k = 0; k < 9; ++k) t.lpf[k] = (float)(lv[k] / 16.0);
  for (int k = 0; k < 9; ++k) t.hpf3[k] = -1.0f;
  t.hpf3[4] = 8.0f;
  for (int k = 0; k < 25; ++k) t.hpf5[k] = -1.0f;
  t.hpf5[12] = 24.0f;
  fill_log(3, 0.8, t.log3);
  fill_log(5, 1.0, t.log5);
  fill_log(7, 1.4, t.log7);
  fill_gabor(0.0, t.gab[0]);
  fill_gabor(45.0, t.gab[1]);
  fill_gabor(90.0, t.gab[2]);
  fill_gabor(135.0, t.gab[3]);
  return t;
}

constexpr KTabs KT = make_tabs();

// ------------------------------- helpers ---------------------------------

__device__ __forceinline__ float fast_tanh(float x) {
  float e = __builtin_amdgcn_exp2f(x * 2.8853900817779268f);
  return 1.0f - 2.0f * __builtin_amdgcn_rcpf(e + 1.0f);
}
__device__ __forceinline__ float squash_from(float z) {
  return fmaf(fast_tanh(0.1f * z), 0.5f, 0.5f);
}

// R0's verified staging: 22 rows x 72 cols, zero-padded at borders.
__device__ __forceinline__ void stage_tile(const float* __restrict__ in,
                                           float* __restrict__ tile, int x0,
                                           int y0, int tid) {
  const int gx0 = x0 - 4;
  const int gy0 = y0 - 3;
  for (int k = tid; k < LDSH * (LDSW / 4); k += NTHREADS) {
    int r = k / (LDSW / 4);
    int cc = (k - r * (LDSW / 4)) * 4;
    int gy = gy0 + r;
    int gx = gx0 + cc;
    float4 v = make_float4(0.f, 0.f, 0.f, 0.f);
    if ((unsigned)gy < IMG_H) {
      const float* rowp = in + (size_t)gy * IMG_W;
      if (gx >= 0 && gx + 3 < IMG_W) {
        v = *(const float4*)(rowp + gx);
      } else {
        if ((unsigned)(gx + 0) < IMG_W) v.x = rowp[gx + 0];
        if ((unsigned)(gx + 1) < IMG_W) v.y = rowp[gx + 1];
        if ((unsigned)(gx + 2) < IMG_W) v.z = rowp[gx + 2];
        if ((unsigned)(gx + 3) < IMG_W) v.w = rowp[gx + 3];
      }
    }
    *(float4*)&tile[r * LDSW + cc] = v;
  }
}

#define LOADW12(ROW)                                                        \
  {                                                                         \
    const float4* p = (const float4*)&tile[(ROW)*LDSW + 4 * tx];            \
    float4 w0 = p[0], w1 = p[1], w2 = p[2];                                 \
    w[0] = w0.x; w[1] = w0.y; w[2] = w0.z; w[3] = w0.w;                     \
    w[4] = w1.x; w[5] = w1.y; w[6] = w1.z; w[7] = w1.w;                     \
    w[8] = w2.x; w[9] = w2.y; w[10] = w2.z; w[11] = w2.w;                   \
  }

// ------------------------- kernel 1: lpf + log ---------------------------
// Accumulators: l7,l5,l3,lp = 16 VGPR -> cap at 6 blocks/CU (<=85 VGPR).

__global__ __launch_bounds__(NTHREADS, 6)
void k_log(const float* __restrict__ x, float* __restrict__ out, int planes) {
  __shared__ float tile[LDSH * LDSW];
  const int tid = threadIdx.x;
  const int tx = tid & 15;
  const int ty = tid >> 4;
  const int x0 = blockIdx.x * TILE_W;
  const int y0 = blockIdx.y * TILE_H;
  const int plane = blockIdx.z;
  const float* __restrict__ in = x + (size_t)plane * (IMG_H * IMG_W);

  stage_tile(in, tile, x0, y0, tid);
  __syncthreads();

  float l7[4] = {}, l5[4] = {}, l3[4] = {}, lp[4] = {};
  float w[12];

#pragma unroll
  for (int ir = 0; ir < 7; ++ir) {
    LOADW12(ty + ir);
#pragma unroll
    for (int dx = 0; dx < 7; ++dx) {
      const float c7 = KT.log7[ir * 7 + dx];
#pragma unroll
      for (int c = 0; c < 4; ++c) l7[c] = fmaf(w[c + dx + 1], c7, l7[c]);
    }
    if (ir >= 1 && ir <= 5) {
      const int kr = ir - 1;
#pragma unroll
      for (int dx = 0; dx < 5; ++dx) {
        const float c5 = KT.log5[kr * 5 + dx];
#pragma unroll
        for (int c = 0; c < 4; ++c) l5[c] = fmaf(w[c + dx + 2], c5, l5[c]);
      }
    }
    if (ir >= 2 && ir <= 4) {
      const int kr = ir - 2;
#pragma unroll
      for (int dx = 0; dx < 3; ++dx) {
        const float cl = KT.lpf[kr * 3 + dx];
        const float c3 = KT.log3[kr * 3 + dx];
#pragma unroll
        for (int c = 0; c < 4; ++c) {
          const float v = w[c + dx + 3];
          lp[c] = fmaf(v, cl, lp[c]);
          l3[c] = fmaf(v, c3, l3[c]);
        }
      }
    }
  }

  const size_t fs = (size_t)planes * (IMG_H * IMG_W);
  const size_t off = (size_t)plane * (IMG_H * IMG_W) +
                     (size_t)(y0 + ty) * IMG_W + (x0 + 4 * tx);

  const float4 orig = *(const float4*)&tile[(ty + 3) * LDSW + 4 * tx + 4];
  *(float4*)(out + off) = orig;

  float lo[4];
#pragma unroll
  for (int c = 0; c < 4; ++c)
    lo[c] = squash_from(fmaxf(fmaxf(l3[c], l5[c]), l7[c]));
  *(float4*)(out + fs + off) = make_float4(lp[0], lp[1], lp[2], lp[3]);
  *(float4*)(out + 2 * fs + off) = make_float4(lo[0], lo[1], lo[2], lo[3]);
}

// ---------------------------- kernel 2: hpf ------------------------------
// Accumulators: h5,h3 = 8 VGPR -> cap at 8 blocks/CU (<=64 VGPR).

__global__ __launch_bounds__(NTHREADS, 8)
void k_hpf(const float* __restrict__ x, float* __restrict__ out, int planes) {
  __shared__ float tile[LDSH * LDSW];
  const int tid = threadIdx.x;
  const int tx = tid & 15;
  const int ty = tid >> 4;
  const int x0 = blockIdx.x * TILE_W;
  const int y0 = blockIdx.y * TILE_H;
  const int plane = blockIdx.z;
  const float* __restrict__ in = x + (size_t)plane * (IMG_H * IMG_W);

  stage_tile(in, tile, x0, y0, tid);
  __syncthreads();

  float h5[4] = {}, h3[4] = {};
  float w[12];

#pragma unroll
  for (int ir = 1; ir <= 5; ++ir) {
    LOADW12(ty + ir);
    const int kr = ir - 1;
#pragma unroll
    for (int dx = 0; dx < 5; ++dx) {
      const float ch5 = KT.hpf5[kr * 5 + dx];
#pragma unroll
      for (int c = 0; c < 4; ++c) h5[c] = fmaf(w[c + dx + 2], ch5, h5[c]);
    }
    if (ir >= 2 && ir <= 4) {
      const int k3 = ir - 2;
#pragma unroll
      for (int dx = 0; dx < 3; ++dx) {
        const float ch3 = KT.hpf3[k3 * 3 + dx];
#pragma unroll
        for (int c = 0; c < 4; ++c) h3[c] = fmaf(w[c + dx + 3], ch3, h3[c]);
      }
    }
  }

  const size_t fs = (size_t)planes * (IMG_H * IMG_W);
  const size_t off = (size_t)plane * (IMG_H * IMG_W) +
                     (size_t)(y0 + ty) * IMG_W + (x0 + 4 * tx);

  float ho[4];
#pragma unroll
  for (int c = 0; c < 4; ++c) ho[c] = squash_from(fmaxf(h3[c], h5[c]));
  *(float4*)(out + 3 * fs + off) = make_float4(ho[0], ho[1], ho[2], ho[3]);
}

// --------------------------- kernel 3: gabor -----------------------------
// Accumulators: g0..g3 = 16 VGPR -> cap at 6 blocks/CU (<=85 VGPR).

__global__ __launch_bounds__(NTHREADS, 6)
void k_gab(const float* __restrict__ x, float* __restrict__ out, int planes) {
  __shared__ float tile[LDSH * LDSW];
  const int tid = threadIdx.x;
  const int tx = tid & 15;
  const int ty = tid >> 4;
  const int x0 = blockIdx.x * TILE_W;
  const int y0 = blockIdx.y * TILE_H;
  const int plane = blockIdx.z;
  const float* __restrict__ in = x + (size_t)plane * (IMG_H * IMG_W);

  stage_tile(in, tile, x0, y0, tid);
  __syncthreads();

  float g0[4] = {}, g1[4] = {}, g2[4] = {}, g3[4] = {};
  float w[12];

#pragma unroll
  for (int ir = 0; ir < 7; ++ir) {
    LOADW12(ty + ir);
#pragma unroll
    for (int dx = 0; dx < 7; ++dx) {
      const float cg0 = KT.gab[0][ir * 7 + dx];
      const float cg1 = KT.gab[1][ir * 7 + dx];
      const float cg2 = KT.gab[2][ir * 7 + dx];
      const float cg3 = KT.gab[3][ir * 7 + dx];
#pragma unroll
      for (int c = 0; c < 4; ++c) {
        const float v = w[c + dx + 1];
        g0[c] = fmaf(v, cg0, g0[c]);
        g1[c] = fmaf(v, cg1, g1[c]);
        g2[c] = fmaf(v, cg2, g2[c]);
        g3[c] = fmaf(v, cg3, g3[c]);
      }
    }
  }

  const size_t fs = (size_t)planes * (IMG_H * IMG_W);
  const size_t off = (size_t)plane * (IMG_H * IMG_W) +
                     (size_t)(y0 + ty) * IMG_W + (x0 + 4 * tx);

  float go[4];
#pragma unroll
  for (int c = 0; c < 4; ++c)
    go[c] = fast_tanh(0.1f * fmaxf(fmaxf(g0[c], g1[c]), fmaxf(g2[c], g3[c])));
  *(float4*)(out + 4 * fs + off) = make_float4(go[0], go[1], go[2], go[3]);
}

extern "C" void kernel_launch(void* const* d_in, const int* in_sizes, int n_in,
                              void* d_out, int out_size, void* d_ws, size_t ws_size,
                              hipStream_t stream) {
  const float* x = (const float*)d_in[0];
  float* out = (float*)d_out;
  const int plane_elems = IMG_H * IMG_W;
  const int planes = in_sizes[0] / plane_elems;               // 16*3 = 48
  const int do_gab = (out_size >= 5 * in_sizes[0]) ? 1 : 0;

  dim3 grid(IMG_W / TILE_W, IMG_H / TILE_H, planes);
  k_log<<<grid, NTHREADS, 0, stream>>>(x, out, planes);
  k_hpf<<<grid, NTHREADS, 0, stream>>>(x, out, planes);
  if (do_gab) k_gab<<<grid, NTHREADS, 0, stream>>>(x, out, planes);
}

// Round 7
// 312.326 us; speedup vs baseline: 1.1322x; 1.1322x over previous
//
#include <hip/hip_runtime.h>

#define IMG_H 512
#define IMG_W 512
#define TILE_W 64
#define TILE_H 16
#define LDSW 72   // 64 + 8 halo/alignment cols
#define LDSH 22   // 16 + 6 halo rows
#define TCOLS 72
#define TROWS 16
#define NSLOTA (TROWS * (TCOLS / 4))   // 288 f4 slots per T plane
#define NTHREADS 256

// ---------------- compile-time coefficient generation --------------------
// Verbatim from the ROUND-1 VERIFIED separable kernel (passed, absmax
// 0.00390625): LoG rank-2 factors, gabor rank-1/2 factors, 3x3 class sums.

constexpr double PI_D = 3.141592653589793238462643383279502884;

constexpr double cexp(double x) {
  double term = 1.0, sum = 1.0;
  for (int n = 1; n < 48; ++n) { term *= x / n; sum += term; }
  return sum;
}
constexpr double ccos(double x) {
  double term = 1.0, sum = 1.0;
  for (int n = 1; n < 24; ++n) {
    term *= -x * x / ((2.0 * n - 1.0) * (2.0 * n));
    sum += term;
  }
  return sum;
}
constexpr double csin(double x) {
  double term = x, sum = x;
  for (int n = 1; n < 24; ++n) {
    term *= -x * x / ((2.0 * n) * (2.0 * n + 1.0));
    sum += term;
  }
  return sum;
}
constexpr double cabs_(double x) { return x < 0 ? -x : x; }

constexpr void fill_log(int ks, double sigma, float* out) {
  double buf[49] = {};
  double s = 0.0;
  const int h = ks / 2;
  for (int i = 0; i < ks; ++i) {
    for (int j = 0; j < ks; ++j) {
      const double xi = (double)(i - h);
      const double yj = (double)(j - h);
      const double r2 = xi * xi + yj * yj;
      const double g = cexp(-r2 / (2.0 * sigma * sigma));
      const double lap = -1.0 / (PI_D * sigma * sigma * sigma * sigma) *
                         (1.0 - r2 / (2.0 * sigma * sigma));
      buf[i * ks + j] = lap * g;
      s += cabs_(lap * g);
    }
  }
  for (int k = 0; k < ks * ks; ++k) out[k] = (float)(buf[k] / s);
}

constexpr void fill_log_sep(int ks, double sigma, float* va, float* g, float* wb) {
  const int h = ks / 2;
  double s = 0.0;
  for (int i = 0; i < ks; ++i)
    for (int j = 0; j < ks; ++j) {
      const double xi = (double)(i - h), yj = (double)(j - h);
      const double r2 = xi * xi + yj * yj;
      const double gg = cexp(-r2 / (2.0 * sigma * sigma));
      const double lap = -1.0 / (PI_D * sigma * sigma * sigma * sigma) *
                         (1.0 - r2 / (2.0 * sigma * sigma));
      s += cabs_(lap * gg);
    }
  const double c = 1.0 / (PI_D * sigma * sigma * sigma * sigma);
  for (int i = 0; i < ks; ++i) {
    const double d = (double)(i - h);
    const double gi = cexp(-d * d / (2.0 * sigma * sigma));
    g[i] = (float)gi;
    va[i] = (float)((-c + c * d * d / (2.0 * sigma * sigma)) * gi / s);
    wb[i] = (float)((c * d * d / (2.0 * sigma * sigma)) * gi / s);
  }
}

constexpr double gabor_norm(double ang_deg) {
  const double th = ang_deg * PI_D / 180.0;
  const double ct = ccos(th), st = csin(th);
  double s = 0.0;
  for (int i = 0; i < 7; ++i)
    for (int j = 0; j < 7; ++j) {
      const double xv = (double)(j - 3);
      const double yv = (double)(i - 3);
      const double xt = xv * ct + yv * st;
      const double yt = -xv * st + yv * ct;
      const double g = cexp(-(xt * xt / 4.0 + yt * yt / 4.0) / 2.0) *
                       ccos(2.0 * PI_D * 0.1 * xt);
      s += cabs_(g);
    }
  return s;
}

struct SepTabs {
  float l5_va[5], l5_g[5], l5_wb[5];
  float l7_va[7], l7_g[7], l7_wb[7];
  float v_gb[7], v_gc0[7], v_gca[7], v_gsa[7];
  float h_g0[7], h_g90[7], h_gc[7], h_gs[7];
  float is45, is135;
  float l3_m, l3_e, l3_s;
};

constexpr SepTabs make_sep() {
  SepTabs t{};
  fill_log_sep(5, 1.0, t.l5_va, t.l5_g, t.l5_wb);
  fill_log_sep(7, 1.4, t.l7_va, t.l7_g, t.l7_wb);
  const double s0 = gabor_norm(0.0), s90 = gabor_norm(90.0);
  const double s45 = gabor_norm(45.0), s135 = gabor_norm(135.0);
  const double th45 = 45.0 * PI_D / 180.0;
  const double a45 = 2.0 * PI_D * 0.1 * ccos(th45);
  const double b45 = 2.0 * PI_D * 0.1 * csin(th45);
  const double w0 = 2.0 * PI_D * 0.1;
  for (int k = 0; k < 7; ++k) {
    const double d = (double)(k - 3);
    const double gg = cexp(-d * d / 8.0);
    t.v_gb[k]  = (float)gg;
    t.v_gc0[k] = (float)(gg * ccos(w0 * d));
    t.v_gca[k] = (float)(gg * ccos(b45 * d));
    t.v_gsa[k] = (float)(gg * csin(b45 * d));
    t.h_g0[k]  = (float)(gg * ccos(w0 * d) / s0);
    t.h_g90[k] = (float)(gg / s90);
    t.h_gc[k]  = (float)(gg * ccos(a45 * d));
    t.h_gs[k]  = (float)(gg * csin(a45 * d));
  }
  t.is45 = (float)(1.0 / s45);
  t.is135 = (float)(1.0 / s135);
  float l3[9] = {};
  fill_log(3, 0.8, l3);
  t.l3_m = l3[4]; t.l3_e = l3[1]; t.l3_s = l3[0];
  return t;
}

constexpr SepTabs ST = make_sep();

// ------------------------------- helpers ---------------------------------

__device__ __forceinline__ float fast_tanh(float x) {
  float e = __builtin_amdgcn_exp2f(x * 2.8853900817779268f);
  return 1.0f - 2.0f * __builtin_amdgcn_rcpf(e + 1.0f);
}
__device__ __forceinline__ float squash_from(float z) {
  return fmaf(fast_tanh(0.1f * z), 0.5f, 0.5f);
}
__device__ __forceinline__ float4 f4z() { return make_float4(0.f, 0.f, 0.f, 0.f); }
__device__ __forceinline__ float4 f4add(float4 a, float4 b) {
  return make_float4(a.x + b.x, a.y + b.y, a.z + b.z, a.w + b.w);
}
__device__ __forceinline__ float4 f4fma(float a, float4 b, float4 c) {
  return make_float4(fmaf(a, b.x, c.x), fmaf(a, b.y, c.y),
                     fmaf(a, b.z, c.z), fmaf(a, b.w, c.w));
}
__device__ __forceinline__ void loadw12(const float* p, float* w) {
  const float4 a = *(const float4*)(p);
  const float4 b = *(const float4*)(p + 4);
  const float4 c = *(const float4*)(p + 8);
  w[0] = a.x; w[1] = a.y; w[2] = a.z; w[3] = a.w;
  w[4] = b.x; w[5] = b.y; w[6] = b.z; w[7] = b.w;
  w[8] = c.x; w[9] = c.y; w[10] = c.z; w[11] = c.w;
}

// ------------------------------- kernel ----------------------------------
// Two-phase separable, T-buffer REUSED between phases:
//   stage tile -> bar
//   A-vert: 5 planes {B5, L5A, L5G, L7A, L7G} -> bar
//   A-horiz: lo/lp/ho/orig computed+stored (T reads, tile 3x3 reads) -> bar
//   B-vert: 4 planes {GB, GC0, GCA, GSA} into same T -> bar
//   B-horiz: go computed+stored.
// LDS = 6336 + 23040 = 29376 B -> 5 blocks/CU; bounds (256,5) caps VGPR<=102.

__global__ __launch_bounds__(NTHREADS, 5)
void msif_kernel(const float* __restrict__ x, float* __restrict__ out,
                 int planes, int do_gab) {
  __shared__ float tile[LDSH * LDSW];      // 6336 B
  __shared__ float T[5][TROWS * TCOLS];    // 23040 B (reused A then B)

  const int tid = threadIdx.x;
  const int tx = tid & 15;
  const int ty = tid >> 4;
  const int x0 = blockIdx.x * TILE_W;
  const int y0 = blockIdx.y * TILE_H;
  const int plane = blockIdx.z;
  const float* __restrict__ in = x + (size_t)plane * (IMG_H * IMG_W);

  // ---- stage input tile (verbatim R0) ----
  const int gx0 = x0 - 4;
  const int gy0 = y0 - 3;
  for (int k = tid; k < LDSH * (LDSW / 4); k += NTHREADS) {
    int r = k / (LDSW / 4);
    int cc = (k - r * (LDSW / 4)) * 4;
    int gy = gy0 + r;
    int gx = gx0 + cc;
    float4 v = make_float4(0.f, 0.f, 0.f, 0.f);
    if ((unsigned)gy < IMG_H) {
      const float* rowp = in + (size_t)gy * IMG_W;
      if (gx >= 0 && gx + 3 < IMG_W) {
        v = *(const float4*)(rowp + gx);
      } else {
        if ((unsigned)(gx + 0) < IMG_W) v.x = rowp[gx + 0];
        if ((unsigned)(gx + 1) < IMG_W) v.y = rowp[gx + 1];
        if ((unsigned)(gx + 2) < IMG_W) v.z = rowp[gx + 2];
        if ((unsigned)(gx + 3) < IMG_W) v.w = rowp[gx + 3];
      }
    }
    *(float4*)&tile[r * LDSW + cc] = v;
  }
  __syncthreads();

  // ---- phase A vertical: B5, L5A, L5G, L7A, L7G ----
  for (int k = tid; k < NSLOTA; k += NTHREADS) {
    const int r = k / (TCOLS / 4);
    const int c4 = (k - r * (TCOLS / 4)) * 4;
    const float* base = &tile[r * LDSW + c4];
    float4 wv[7];
#pragma unroll
    for (int i = 0; i < 7; ++i) wv[i] = *(const float4*)(base + i * LDSW);

    float4 b5 = f4add(f4add(wv[1], wv[2]), f4add(f4add(wv[3], wv[4]), wv[5]));
    float4 l5a = f4z(), l5g = f4z();
#pragma unroll
    for (int i = 0; i < 5; ++i) {
      l5a = f4fma(ST.l5_va[i], wv[i + 1], l5a);
      l5g = f4fma(ST.l5_g[i],  wv[i + 1], l5g);
    }
    float4 l7a = f4z(), l7g = f4z();
#pragma unroll
    for (int i = 0; i < 7; ++i) {
      l7a = f4fma(ST.l7_va[i], wv[i], l7a);
      l7g = f4fma(ST.l7_g[i],  wv[i], l7g);
    }
    const int o = r * TCOLS + c4;
    *(float4*)&T[0][o] = b5;
    *(float4*)&T[1][o] = l5a;
    *(float4*)&T[2][o] = l5g;
    *(float4*)&T[3][o] = l7a;
    *(float4*)&T[4][o] = l7g;
  }
  __syncthreads();

  const size_t fs = (size_t)planes * (IMG_H * IMG_W);
  const size_t off = (size_t)plane * (IMG_H * IMG_W) +
                     (size_t)(y0 + ty) * IMG_W + (x0 + 4 * tx);
  const int toff = ty * TCOLS + 4 * tx;

  // ---- phase A horizontal + 3x3 direct + stores (orig, lpf, log, hpf) ----
  {
    float w[12];
    float l7[4] = {}, l5[4] = {}, box[4];

    loadw12(&T[3][toff], w);               // L7A * g
#pragma unroll
    for (int dx = 0; dx < 7; ++dx) {
      const float cc = ST.l7_g[dx];
#pragma unroll
      for (int c = 0; c < 4; ++c) l7[c] = fmaf(w[c + dx + 1], cc, l7[c]);
    }
    loadw12(&T[4][toff], w);               // L7G * wb
#pragma unroll
    for (int dx = 0; dx < 7; ++dx) {
      const float cc = ST.l7_wb[dx];
#pragma unroll
      for (int c = 0; c < 4; ++c) l7[c] = fmaf(w[c + dx + 1], cc, l7[c]);
    }
    loadw12(&T[1][toff], w);               // L5A * g
#pragma unroll
    for (int dx = 0; dx < 5; ++dx) {
      const float cc = ST.l5_g[dx];
#pragma unroll
      for (int c = 0; c < 4; ++c) l5[c] = fmaf(w[c + dx + 2], cc, l5[c]);
    }
    loadw12(&T[2][toff], w);               // L5G * wb
#pragma unroll
    for (int dx = 0; dx < 5; ++dx) {
      const float cc = ST.l5_wb[dx];
#pragma unroll
      for (int c = 0; c < 4; ++c) l5[c] = fmaf(w[c + dx + 2], cc, l5[c]);
    }
    loadw12(&T[0][toff], w);               // B5 horizontal box
#pragma unroll
    for (int c = 0; c < 4; ++c)
      box[c] = ((w[c + 2] + w[c + 3]) + (w[c + 4] + w[c + 5])) + w[c + 6];

    // 3x3 class sums from input tile (rows ty+2..ty+4)
    float m[4], e[4], s[4];
    loadw12(&tile[(ty + 2) * LDSW + 4 * tx], w);
#pragma unroll
    for (int c = 0; c < 4; ++c) {
      e[c] = w[c + 4];
      s[c] = w[c + 3] + w[c + 5];
    }
    loadw12(&tile[(ty + 4) * LDSW + 4 * tx], w);
#pragma unroll
    for (int c = 0; c < 4; ++c) {
      e[c] += w[c + 4];
      s[c] += w[c + 3] + w[c + 5];
    }
    loadw12(&tile[(ty + 3) * LDSW + 4 * tx], w);
    *(float4*)(out + off) = make_float4(w[4], w[5], w[6], w[7]);  // original
#pragma unroll
    for (int c = 0; c < 4; ++c) {
      m[c] = w[c + 4];
      e[c] += w[c + 3] + w[c + 5];
    }

    float lp[4], lo[4], ho[4];
#pragma unroll
    for (int c = 0; c < 4; ++c) {
      lp[c] = fmaf(0.25f, m[c], fmaf(0.125f, e[c], 0.0625f * s[c]));
      const float l3v = fmaf(ST.l3_m, m[c], fmaf(ST.l3_e, e[c], ST.l3_s * s[c]));
      const float h3v = fmaf(8.f, m[c], -(e[c] + s[c]));
      const float h5v = fmaf(25.f, m[c], -box[c]);
      lo[c] = squash_from(fmaxf(fmaxf(l3v, l5[c]), l7[c]));
      ho[c] = squash_from(fmaxf(h3v, h5v));
    }
    *(float4*)(out + fs + off) = make_float4(lp[0], lp[1], lp[2], lp[3]);
    *(float4*)(out + 2 * fs + off) = make_float4(lo[0], lo[1], lo[2], lo[3]);
    *(float4*)(out + 3 * fs + off) = make_float4(ho[0], ho[1], ho[2], ho[3]);
  }

  if (!do_gab) return;
  __syncthreads();   // all T reads of phase A done before overwrite

  // ---- phase B vertical: GB, GC0, GCA, GSA into reused T ----
  for (int k = tid; k < NSLOTA; k += NTHREADS) {
    const int r = k / (TCOLS / 4);
    const int c4 = (k - r * (TCOLS / 4)) * 4;
    const float* base = &tile[r * LDSW + c4];
    float4 gb = f4z(), gc0 = f4z(), gca = f4z(), gsa = f4z();
#pragma unroll
    for (int i = 0; i < 7; ++i) {
      const float4 wv = *(const float4*)(base + i * LDSW);
      gb  = f4fma(ST.v_gb[i],  wv, gb);
      gc0 = f4fma(ST.v_gc0[i], wv, gc0);
      gca = f4fma(ST.v_gca[i], wv, gca);
      gsa = f4fma(ST.v_gsa[i], wv, gsa);
    }
    const int o = r * TCOLS + c4;
    *(float4*)&T[0][o] = gb;
    *(float4*)&T[1][o] = gc0;
    *(float4*)&T[2][o] = gca;
    *(float4*)&T[3][o] = gsa;
  }
  __syncthreads();

  // ---- phase B horizontal + store (gabor) ----
  {
    float w[12];
    float g0[4] = {}, g90[4] = {}, Pa[4] = {}, Qa[4] = {};

    loadw12(&T[0][toff], w);
#pragma unroll
    for (int dx = 0; dx < 7; ++dx) {
      const float cc = ST.h_g0[dx];
#pragma unroll
      for (int c = 0; c < 4; ++c) g0[c] = fmaf(w[c + dx + 1], cc, g0[c]);
    }
    loadw12(&T[1][toff], w);
#pragma unroll
    for (int dx = 0; dx < 7; ++dx) {
      const float cc = ST.h_g90[dx];
#pragma unroll
      for (int c = 0; c < 4; ++c) g90[c] = fmaf(w[c + dx + 1], cc, g90[c]);
    }
    loadw12(&T[2][toff], w);
#pragma unroll
    for (int dx = 0; dx < 7; ++dx) {
      const float cc = ST.h_gc[dx];
#pragma unroll
      for (int c = 0; c < 4; ++c) Pa[c] = fmaf(w[c + dx + 1], cc, Pa[c]);
    }
    loadw12(&T[3][toff], w);
#pragma unroll
    for (int dx = 0; dx < 7; ++dx) {
      const float cc = ST.h_gs[dx];
#pragma unroll
      for (int c = 0; c < 4; ++c) Qa[c] = fmaf(w[c + dx + 1], cc, Qa[c]);
    }

    float go[4];
#pragma unroll
    for (int c = 0; c < 4; ++c) {
      const float o45  = (Pa[c] - Qa[c]) * ST.is45;
      const float o135 = (Pa[c] + Qa[c]) * ST.is135;
      go[c] = fast_tanh(0.1f * fmaxf(fmaxf(g0[c], g90[c]), fmaxf(o45, o135)));
    }
    *(float4*)(out + 4 * fs + off) = make_float4(go[0], go[1], go[2], go[3]);
  }
}

extern "C" void kernel_launch(void* const* d_in, const int* in_sizes, int n_in,
                              void* d_out, int out_size, void* d_ws, size_t ws_size,
                              hipStream_t stream) {
  const float* x = (const float*)d_in[0];
  float* out = (float*)d_out;
  const int plane_elems = IMG_H * IMG_W;
  const int planes = in_sizes[0] / plane_elems;               // 16*3 = 48
  const int do_gab = (out_size >= 5 * in_sizes[0]) ? 1 : 0;

  dim3 grid(IMG_W / TILE_W, IMG_H / TILE_H, planes);
  msif_kernel<<<grid, NTHREADS, 0, stream>>>(x, out, planes, do_gab);
}